// Round 6
// baseline (617.864 us; speedup 1.0000x reference)
//
// Ernie4.5 MoE MLP — MI355X gfx950
// R6: kill the tr_b16 path (m217: simple-subtiled tr reads are ~4-way conflicted,
//     invisible in PMC). wcvt now converts AND transposes weights (bf16 [n][k]),
//     so both GEMMs are exact m97 replicas: A and B tiles [128][64], same XOR
//     swizzle, global_load_lds w16 staging, ds_read_b128 fragments, single
//     buffer, plain __syncthreads. Fragment elements identical to R2-verified.
// ws peak ~261 MB. eo aliases adisp (dead after gemm1).
#include <hip/hip_runtime.h>
#include <hip/hip_bf16.h>

constexpr int S_TOK = 16384;
constexpr int HDIM  = 1024;
constexpr int IDIM  = 512;
constexpr int NEXP  = 64;
constexpr int CAPC  = 640;
constexpr int NCHUNK = 128;   // 32768 routing entries / 256

typedef __attribute__((ext_vector_type(8))) short bf16x8;
typedef __attribute__((ext_vector_type(4))) float f32x4;

__device__ __forceinline__ float bf2f(unsigned short u){
  return __uint_as_float(((unsigned)u) << 16);
}
__device__ __forceinline__ unsigned short f2bf(float f){   // RNE bf16 (inputs finite)
  unsigned u = __float_as_uint(f);
  return (unsigned short)((u + 0x7fffu + ((u >> 16) & 1u)) >> 16);
}
__device__ __forceinline__ void gload_lds16(const void* g, void* l){
  __builtin_amdgcn_global_load_lds((const __attribute__((address_space(1))) unsigned*)g,
                                   (__attribute__((address_space(3))) unsigned*)l, 16, 0, 0);
}

// ---------------- weight fp32 [R][C] -> bf16 transposed [C][R] ----------------
__global__ __launch_bounds__(256) void wcvtT_kernel(const float* __restrict__ src,
                                                    unsigned short* __restrict__ dst,
                                                    int R, int C)
{
  __shared__ unsigned short ls[64 * 72];     // [r][c], stride 72 (pad)
  const int tilesC = C >> 6;
  const int tpe = (R >> 6) * tilesC;
  const int b = blockIdx.x;
  const int e = b / tpe, rem = b - e * tpe;
  const int r0 = (rem / tilesC) * 64, c0 = (rem % tilesC) * 64;
  const float* sp = src + (size_t)e * R * C + (size_t)r0 * C + c0;
  unsigned short* dp = dst + (size_t)e * R * C + (size_t)c0 * R + r0;
  const int t = threadIdx.x;
  const int rsub = t >> 4, cs = (t & 15) * 4;
#pragma unroll
  for (int q = 0; q < 4; ++q){
    int r = rsub * 4 + q;
    float4 v = *(const float4*)(sp + (size_t)r * C + cs);
    unsigned short* lp = &ls[r * 72 + cs];
    lp[0] = f2bf(v.x); lp[1] = f2bf(v.y); lp[2] = f2bf(v.z); lp[3] = f2bf(v.w);
  }
  __syncthreads();
  const int c = t >> 2, rs = (t & 3) * 16;
  unsigned vv[16];
#pragma unroll
  for (int j = 0; j < 16; ++j) vv[j] = ls[(rs + j) * 72 + c];
  uint4 o0 = make_uint4(vv[0]|(vv[1]<<16),  vv[2]|(vv[3]<<16),
                        vv[4]|(vv[5]<<16),  vv[6]|(vv[7]<<16));
  uint4 o1 = make_uint4(vv[8]|(vv[9]<<16),  vv[10]|(vv[11]<<16),
                        vv[12]|(vv[13]<<16), vv[14]|(vv[15]<<16));
  *(uint4*)(dp + (size_t)c * R + rs)     = o0;
  *(uint4*)(dp + (size_t)c * R + rs + 8) = o1;
}

// ---------------- gate: logits (fp32 exact), softmax, top-2 -------------------
__global__ __launch_bounds__(256) void gate_kernel(
    const float* __restrict__ x, const float* __restrict__ wgate,
    float* __restrict__ logits_out, float* __restrict__ topk_p,
    int* __restrict__ flat_e, float* __restrict__ rl_out)
{
  __shared__ float xs[4][HDIM];
  const int w = threadIdx.x >> 6, lane = threadIdx.x & 63;
  const int tok = blockIdx.x * 4 + w;
  const float4* xr = (const float4*)(x + (size_t)tok * HDIM);
  float4* xd = (float4*)(&xs[w][0]);
#pragma unroll
  for (int j = 0; j < 4; ++j) xd[j * 64 + lane] = xr[j * 64 + lane];
  __syncthreads();
  float acc = 0.f;
#pragma unroll 8
  for (int h = 0; h < HDIM; ++h)
    acc = fmaf(xs[w][h], wgate[h * NEXP + lane], acc);
  logits_out[(size_t)tok * NEXP + lane] = acc;
  float m = acc;
#pragma unroll
  for (int d = 1; d < 64; d <<= 1) m = fmaxf(m, __shfl_xor(m, d));
  float p = expf(acc - m);
  float sum = p;
#pragma unroll
  for (int d = 1; d < 64; d <<= 1) sum += __shfl_xor(sum, d);
  float prob = p / sum;
  float v = prob; int idx = lane;
#pragma unroll
  for (int d = 1; d < 64; d <<= 1){
    float ov = __shfl_xor(v, d); int oi = __shfl_xor(idx, d);
    if (ov > v || (ov == v && oi < idx)){ v = ov; idx = oi; }
  }
  const int e1 = idx; const float p1 = v;
  v = (lane == e1) ? -1.f : prob; idx = lane;
#pragma unroll
  for (int d = 1; d < 64; d <<= 1){
    float ov = __shfl_xor(v, d); int oi = __shfl_xor(idx, d);
    if (ov > v || (ov == v && oi < idx)){ v = ov; idx = oi; }
  }
  if (lane == 0){
    flat_e[tok * 2]     = e1;  flat_e[tok * 2 + 1] = idx;
    topk_p[tok * 2]     = p1;  topk_p[tok * 2 + 1] = v;
  }
  if (tok == 0 && lane == 0) rl_out[0] = 0.f;
}

// ---------------- per-chunk expert histogram ---------------------------------
__global__ __launch_bounds__(256) void hist_kernel(const int* __restrict__ flat_e,
                                                   int* __restrict__ counts)
{
  __shared__ int hh[NEXP];
  const int t = threadIdx.x;
  if (t < NEXP) hh[t] = 0;
  __syncthreads();
  const int e = flat_e[blockIdx.x * 256 + t];
  atomicAdd(&hh[e], 1);
  __syncthreads();
  if (t < NEXP) counts[blockIdx.x * NEXP + t] = hh[t];
}

// ---------------- per-expert exclusive scan over chunks ----------------------
__global__ __launch_bounds__(256) void offsets_kernel(const int* __restrict__ counts,
                                                      int* __restrict__ offs,
                                                      int* __restrict__ etot)
{
  const int w = threadIdx.x >> 6, lane = threadIdx.x & 63;
  const int e = blockIdx.x * 4 + w;
  int v0 = counts[lane * NEXP + e];
  int v1 = counts[(64 + lane) * NEXP + e];
  int s0 = v0, s1 = v1;
#pragma unroll
  for (int d = 1; d < 64; d <<= 1){
    int n0 = __shfl_up(s0, d); if (lane >= d) s0 += n0;
    int n1 = __shfl_up(s1, d); if (lane >= d) s1 += n1;
  }
  const int tot0 = __shfl(s0, 63);
  offs[lane * NEXP + e]        = s0 - v0;
  offs[(64 + lane) * NEXP + e] = tot0 + s1 - v1;
  if (lane == 63) etot[e] = tot0 + s1;
}

// ---------------- ordered placement + slot map + cw --------------------------
__global__ __launch_bounds__(256) void place_kernel(
    const int* __restrict__ flat_e, const float* __restrict__ topk_p,
    const int* __restrict__ offs, int* __restrict__ entry_slot,
    int* __restrict__ token_of_slot, float* __restrict__ cw_out)
{
  __shared__ int es[256];
  __shared__ float wsh[256];
  const int t = threadIdx.x;
  const int i = blockIdx.x * 256 + t;
  const int e = flat_e[i];
  es[t] = e;
  __syncthreads();
  int local = 0;
  for (int j = 0; j < t; ++j) local += (es[j] == e);
  const int pos = offs[blockIdx.x * NEXP + e] + local;
  const bool valid = pos < CAPC;
  const int slot = e * CAPC + pos;
  entry_slot[i] = valid ? slot : -1;
  if (valid) token_of_slot[slot] = i >> 1;
  const float p = topk_p[i];
  wsh[t] = valid ? p : 0.f;
  __syncthreads();
  const float wme = wsh[t], wo = wsh[t ^ 1];
  cw_out[i] = wme / fmaxf(wme + wo, 1e-12f);
}

// ---------------- build dispatched A (bf16) ----------------------------------
__global__ __launch_bounds__(256) void adisp_kernel(
    const float* __restrict__ x, const int* __restrict__ token_of_slot,
    const int* __restrict__ etot, unsigned short* __restrict__ adisp)
{
  const int slot = blockIdx.x;
  const int e = slot / CAPC, c = slot - e * CAPC;
  int cnt = etot[e]; if (cnt > CAPC) cnt = CAPC;
  if (c >= cnt) return;
  const int tok = token_of_slot[slot];
  const int t = threadIdx.x;
  float4 v = ((const float4*)(x + (size_t)tok * HDIM))[t];
  ushort4 o; o.x = f2bf(v.x); o.y = f2bf(v.y); o.z = f2bf(v.z); o.w = f2bf(v.w);
  ((ushort4*)(adisp + (size_t)slot * HDIM))[t] = o;
}

// Both tiles [128 rows][64 k] bf16: staged by gload_lds w16, linear LDS dest,
// source octet pre-swizzled: unit c -> row=c>>3, jsrc=(c&7)^(row&7) (rule 21).
// Fragment read: ds_read_b128 at row*64 + ((ks*4+(lane>>4)) ^ (row&7))*8.
// This is the m97 structure for both A and B (B stored transposed [n][k]).

// ---------------- gemm1: fused g,u = A*Wg, A*Wu ; h = silu(g)*u (bf16) -------
__global__ __launch_bounds__(256, 3) void gemm1_kernel(
    const unsigned short* __restrict__ adisp,
    const unsigned short* __restrict__ wgt, const unsigned short* __restrict__ wut,
    unsigned short* __restrict__ hbuf)
{
  __shared__ unsigned short As[128 * 64];
  __shared__ unsigned short Bgs[128 * 64];
  __shared__ unsigned short Bus[128 * 64];
  const int bb = blockIdx.x;
  const int lb = (bb & 7) * 160 + (bb >> 3);         // 1280 blocks, 1280%8==0
  const int e = lb / 20; const int r2 = lb - e * 20;
  const int nt = r2 / 5, mt = r2 - nt * 5;           // mt innermost: 5 blocks share B
  const int t = threadIdx.x, w = t >> 6, lane = t & 63;
  const int wr = w >> 1, wc = w & 1;
  const size_t arow0 = (size_t)e * CAPC + (size_t)mt * 128;
  const unsigned short* abase = adisp + arow0 * HDIM;
  const unsigned short* bg = wgt + ((size_t)e * IDIM + nt * 128) * HDIM;
  const unsigned short* bu = wut + ((size_t)e * IDIM + nt * 128) * HDIM;

  int soff[4];
#pragma unroll
  for (int rr = 0; rr < 4; ++rr){
    int c = rr * 256 + t;
    int row = c >> 3;
    int jsrc = (c & 7) ^ (row & 7);
    soff[rr] = row * HDIM + jsrc * 8;
  }

  f32x4 accg[4][4], accu[4][4];
#pragma unroll
  for (int i = 0; i < 4; ++i)
#pragma unroll
    for (int j = 0; j < 4; ++j)
#pragma unroll
      for (int q = 0; q < 4; ++q){ accg[i][j][q] = 0.f; accu[i][j][q] = 0.f; }

  for (int kb = 0; kb < HDIM; kb += 64){
    __syncthreads();
#pragma unroll
    for (int rr = 0; rr < 4; ++rr)
      gload_lds16(abase + soff[rr] + kb, &As[(rr * 256 + w * 64) * 8]);
#pragma unroll
    for (int rr = 0; rr < 4; ++rr)
      gload_lds16(bg + soff[rr] + kb, &Bgs[(rr * 256 + w * 64) * 8]);
#pragma unroll
    for (int rr = 0; rr < 4; ++rr)
      gload_lds16(bu + soff[rr] + kb, &Bus[(rr * 256 + w * 64) * 8]);
    __syncthreads();

#pragma unroll
    for (int ks = 0; ks < 2; ++ks){
      const int j8 = ks * 4 + (lane >> 4);
      bf16x8 af[4], bfr[4];
#pragma unroll
      for (int m = 0; m < 4; ++m){
        int row = wr * 64 + m * 16 + (lane & 15);
        af[m] = *(const bf16x8*)&As[row * 64 + ((j8 ^ (row & 7)) * 8)];
      }
#pragma unroll
      for (int n = 0; n < 4; ++n){
        int brow = wc * 64 + n * 16 + (lane & 15);
        bfr[n] = *(const bf16x8*)&Bgs[brow * 64 + ((j8 ^ (brow & 7)) * 8)];
      }
#pragma unroll
      for (int m = 0; m < 4; ++m)
#pragma unroll
        for (int n = 0; n < 4; ++n)
          accg[m][n] = __builtin_amdgcn_mfma_f32_16x16x32_bf16(af[m], bfr[n], accg[m][n], 0, 0, 0);
#pragma unroll
      for (int n = 0; n < 4; ++n){
        int brow = wc * 64 + n * 16 + (lane & 15);
        bfr[n] = *(const bf16x8*)&Bus[brow * 64 + ((j8 ^ (brow & 7)) * 8)];
      }
#pragma unroll
      for (int m = 0; m < 4; ++m)
#pragma unroll
        for (int n = 0; n < 4; ++n)
          accu[m][n] = __builtin_amdgcn_mfma_f32_16x16x32_bf16(af[m], bfr[n], accu[m][n], 0, 0, 0);
    }
  }
  // epilogue: h = silu(g)*u -> bf16
#pragma unroll
  for (int m = 0; m < 4; ++m)
#pragma unroll
    for (int n = 0; n < 4; ++n)
#pragma unroll
      for (int q = 0; q < 4; ++q){
        int row = wr * 64 + m * 16 + (lane >> 4) * 4 + q;
        int col = nt * 128 + wc * 64 + n * 16 + (lane & 15);
        float gv = accg[m][n][q], uv = accu[m][n][q];
        float hv = gv / (1.f + expf(-gv)) * uv;
        hbuf[(arow0 + row) * IDIM + col] = f2bf(hv);
      }
}

// ---------------- gemm2: eo = h * Wd (bf16 out) ------------------------------
__global__ __launch_bounds__(256, 3) void gemm2_kernel(
    const unsigned short* __restrict__ hbuf,
    const unsigned short* __restrict__ wdt,
    unsigned short* __restrict__ eo)
{
  __shared__ unsigned short As[128 * 64];
  __shared__ unsigned short Bs[128 * 64];
  const int bb = blockIdx.x;
  const int lb = (bb & 7) * 320 + (bb >> 3);         // 2560 blocks, 2560%8==0
  const int e = lb / 40; const int r2 = lb - e * 40;
  const int nt = r2 / 5, mt = r2 - nt * 5;
  const int t = threadIdx.x, w = t >> 6, lane = t & 63;
  const int wr = w >> 1, wc = w & 1;
  const size_t arow0 = (size_t)e * CAPC + (size_t)mt * 128;
  const unsigned short* abase = hbuf + arow0 * IDIM;
  const unsigned short* bd = wdt + ((size_t)e * HDIM + nt * 128) * IDIM;

  int soff[4];
#pragma unroll
  for (int rr = 0; rr < 4; ++rr){
    int c = rr * 256 + t;
    int row = c >> 3;
    int jsrc = (c & 7) ^ (row & 7);
    soff[rr] = row * IDIM + jsrc * 8;
  }

  f32x4 acc[4][4];
#pragma unroll
  for (int i = 0; i < 4; ++i)
#pragma unroll
    for (int j = 0; j < 4; ++j)
#pragma unroll
      for (int q = 0; q < 4; ++q) acc[i][j][q] = 0.f;

  for (int kb = 0; kb < IDIM; kb += 64){
    __syncthreads();
#pragma unroll
    for (int rr = 0; rr < 4; ++rr)
      gload_lds16(abase + soff[rr] + kb, &As[(rr * 256 + w * 64) * 8]);
#pragma unroll
    for (int rr = 0; rr < 4; ++rr)
      gload_lds16(bd + soff[rr] + kb, &Bs[(rr * 256 + w * 64) * 8]);
    __syncthreads();

#pragma unroll
    for (int ks = 0; ks < 2; ++ks){
      const int j8 = ks * 4 + (lane >> 4);
      bf16x8 af[4], bfr[4];
#pragma unroll
      for (int m = 0; m < 4; ++m){
        int row = wr * 64 + m * 16 + (lane & 15);
        af[m] = *(const bf16x8*)&As[row * 64 + ((j8 ^ (row & 7)) * 8)];
      }
#pragma unroll
      for (int n = 0; n < 4; ++n){
        int brow = wc * 64 + n * 16 + (lane & 15);
        bfr[n] = *(const bf16x8*)&Bs[brow * 64 + ((j8 ^ (brow & 7)) * 8)];
      }
#pragma unroll
      for (int m = 0; m < 4; ++m)
#pragma unroll
        for (int n = 0; n < 4; ++n)
          acc[m][n] = __builtin_amdgcn_mfma_f32_16x16x32_bf16(af[m], bfr[n], acc[m][n], 0, 0, 0);
    }
  }
#pragma unroll
  for (int m = 0; m < 4; ++m)
#pragma unroll
    for (int n = 0; n < 4; ++n)
#pragma unroll
      for (int q = 0; q < 4; ++q){
        int row = wr * 64 + m * 16 + (lane >> 4) * 4 + q;
        int col = nt * 128 + wc * 64 + n * 16 + (lane & 15);
        eo[(arow0 + row) * HDIM + col] = f2bf(acc[m][n][q]);
      }
}

// ---------------- combine: out[s] = sum_k cw[s,k] * eo[slot(s,k)] ------------
__global__ __launch_bounds__(256) void combine_kernel(
    const unsigned short* __restrict__ eo, const int* __restrict__ entry_slot,
    const float* __restrict__ cw, float* __restrict__ out)
{
  const int s = blockIdx.x, t = threadIdx.x;
  const int s0 = entry_slot[2 * s], s1 = entry_slot[2 * s + 1];
  const float w0 = cw[2 * s], w1 = cw[2 * s + 1];
  const int c = t * 4;
  float r0 = 0.f, r1 = 0.f, r2 = 0.f, r3 = 0.f;
  if (s0 >= 0){
    ushort4 vq = *(const ushort4*)&eo[(size_t)s0 * HDIM + c];
    r0 += w0 * bf2f(vq.x); r1 += w0 * bf2f(vq.y); r2 += w0 * bf2f(vq.z); r3 += w0 * bf2f(vq.w);
  }
  if (s1 >= 0){
    ushort4 vq = *(const ushort4*)&eo[(size_t)s1 * HDIM + c];
    r0 += w1 * bf2f(vq.x); r1 += w1 * bf2f(vq.y); r2 += w1 * bf2f(vq.z); r3 += w1 * bf2f(vq.w);
  }
  ((float4*)(out + (size_t)s * HDIM))[t] = make_float4(r0, r1, r2, r3);
}

extern "C" void kernel_launch(void* const* d_in, const int* in_sizes, int n_in,
                              void* d_out, int out_size, void* d_ws, size_t ws_size,
                              hipStream_t stream) {
  (void)in_sizes; (void)n_in; (void)out_size; (void)ws_size;
  const float* x     = (const float*)d_in[0];
  const float* wgate = (const float*)d_in[1];
  const float* wg    = (const float*)d_in[2];
  const float* wu    = (const float*)d_in[3];
  const float* wd    = (const float*)d_in[4];

  float* out        = (float*)d_out;                         // [S,H]
  float* cw_out     = out + (size_t)S_TOK * HDIM;            // [S,2]
  float* rl_out     = cw_out + (size_t)S_TOK * 2;            // [1]
  float* logits_out = rl_out + 1;                            // [S,64]

  char* w8 = (char*)d_ws;
  size_t off = 0;
  auto alloc = [&](size_t bytes){ size_t r = off; off += (bytes + 255) & ~(size_t)255; return r; };
  int*   flat_e_ws        = (int*)  (w8 + alloc((size_t)32768 * 4));
  float* topk_p_ws        = (float*)(w8 + alloc((size_t)32768 * 4));
  int*   counts_ws        = (int*)  (w8 + alloc((size_t)NCHUNK * NEXP * 4));
  int*   offs_ws          = (int*)  (w8 + alloc((size_t)NCHUNK * NEXP * 4));
  int*   etot_ws          = (int*)  (w8 + alloc((size_t)NEXP * 4));
  int*   entry_slot_ws    = (int*)  (w8 + alloc((size_t)32768 * 4));
  int*   token_of_slot_ws = (int*)  (w8 + alloc((size_t)NEXP * CAPC * 4));
  unsigned short* hbuf_ws = (unsigned short*)(w8 + alloc((size_t)NEXP * CAPC * IDIM * 2));
  unsigned short* adisp_ws= (unsigned short*)(w8 + alloc((size_t)NEXP * CAPC * HDIM * 2));
  unsigned short* wbfA_ws = (unsigned short*)(w8 + alloc((size_t)NEXP * HDIM * IDIM * 2));
  unsigned short* wbfU_ws = (unsigned short*)(w8 + alloc((size_t)NEXP * HDIM * IDIM * 2));
  unsigned short* eo_ws   = adisp_ws;   // alias: adisp dead after gemm1

  gate_kernel   <<<S_TOK / 4, 256, 0, stream>>>(x, wgate, logits_out, topk_p_ws, flat_e_ws, rl_out);
  hist_kernel   <<<NCHUNK,    256, 0, stream>>>(flat_e_ws, counts_ws);
  offsets_kernel<<<16,        256, 0, stream>>>(counts_ws, offs_ws, etot_ws);
  place_kernel  <<<NCHUNK,    256, 0, stream>>>(flat_e_ws, topk_p_ws, offs_ws,
                                                entry_slot_ws, token_of_slot_ws, cw_out);
  adisp_kernel  <<<NEXP * CAPC, 256, 0, stream>>>(x, token_of_slot_ws, etot_ws, adisp_ws);
  // transpose-convert: wg,wu [H][I] -> [I][H]; wd [I][H] -> [H][I]
  wcvtT_kernel  <<<NEXP * 128, 256, 0, stream>>>(wg, wbfA_ws, HDIM, IDIM);
  wcvtT_kernel  <<<NEXP * 128, 256, 0, stream>>>(wu, wbfU_ws, HDIM, IDIM);
  gemm1_kernel  <<<NEXP * 20, 256, 0, stream>>>(adisp_ws, wbfA_ws, wbfU_ws, hbuf_ws);
  wcvtT_kernel  <<<NEXP * 128, 256, 0, stream>>>(wd, wbfA_ws, IDIM, HDIM);   // reuse buffer
  gemm2_kernel  <<<NEXP * 40, 256, 0, stream>>>(hbuf_ws, wbfA_ws, eo_ws);
  combine_kernel<<<S_TOK,     256, 0, stream>>>(eo_ws, entry_slot_ws, cw_out, out);
}

// Round 7
// 570.320 us; speedup vs baseline: 1.0834x; 1.0834x over previous
//
// Ernie4.5 MoE MLP — MI355X gfx950
// R7: true T3+T4: 3-stage LDS pipeline, prefetch distance 2, ONE barrier/iter,
//     counted vmcnt (never drains in-loop). wg|wu merged into one interleaved
//     transposed tensor (one B stream, 10 blocks share each 512KB panel).
//     gemm1: M-tile 64, B-tile 256 (g128+u128), grid 2560. gemm2: 3-stage too.
// ws peak ~250 MB. eo aliases adisp; wdt aliases wgu (dead after gemm1).
#include <hip/hip_runtime.h>
#include <hip/hip_bf16.h>

constexpr int S_TOK = 16384;
constexpr int HDIM  = 1024;
constexpr int IDIM  = 512;
constexpr int NEXP  = 64;
constexpr int CAPC  = 640;
constexpr int NCHUNK = 128;   // 32768 routing entries / 256

typedef __attribute__((ext_vector_type(8))) short bf16x8;
typedef __attribute__((ext_vector_type(4))) float f32x4;

__device__ __forceinline__ float bf2f(unsigned short u){
  return __uint_as_float(((unsigned)u) << 16);
}
__device__ __forceinline__ unsigned short f2bf(float f){   // RNE bf16 (inputs finite)
  unsigned u = __float_as_uint(f);
  return (unsigned short)((u + 0x7fffu + ((u >> 16) & 1u)) >> 16);
}
__device__ __forceinline__ void gload_lds16(const void* g, void* l){
  __builtin_amdgcn_global_load_lds((const __attribute__((address_space(1))) unsigned*)g,
                                   (__attribute__((address_space(3))) unsigned*)l, 16, 0, 0);
}

// ---------------- weight fp32 [R][C] -> bf16 transposed, column remap --------
// dst row n' = (n>>7)*ostep + oofs + (n&127); dst layout [e][*][R]
__global__ __launch_bounds__(256) void wcvtT_kernel(const float* __restrict__ src,
                                                    unsigned short* __restrict__ dst,
                                                    int R, int C, int ostep, int oofs,
                                                    size_t dexp)
{
  __shared__ unsigned short ls[64 * 72];     // [r][c], stride 72 (pad)
  const int tilesC = C >> 6;
  const int tpe = (R >> 6) * tilesC;
  const int b = blockIdx.x;
  const int e = b / tpe, rem = b - e * tpe;
  const int r0 = (rem / tilesC) * 64, c0 = (rem % tilesC) * 64;
  const float* sp = src + (size_t)e * R * C + (size_t)r0 * C + c0;
  const int npb = (c0 >> 7) * ostep + oofs + (c0 & 127);
  unsigned short* dp = dst + (size_t)e * dexp + (size_t)npb * R + r0;
  const int t = threadIdx.x;
  const int rsub = t >> 4, cs = (t & 15) * 4;
#pragma unroll
  for (int q = 0; q < 4; ++q){
    int r = rsub * 4 + q;
    float4 v = *(const float4*)(sp + (size_t)r * C + cs);
    unsigned short* lp = &ls[r * 72 + cs];
    lp[0] = f2bf(v.x); lp[1] = f2bf(v.y); lp[2] = f2bf(v.z); lp[3] = f2bf(v.w);
  }
  __syncthreads();
  const int c = t >> 2, rs = (t & 3) * 16;
  unsigned vv[16];
#pragma unroll
  for (int j = 0; j < 16; ++j) vv[j] = ls[(rs + j) * 72 + c];
  uint4 o0 = make_uint4(vv[0]|(vv[1]<<16),  vv[2]|(vv[3]<<16),
                        vv[4]|(vv[5]<<16),  vv[6]|(vv[7]<<16));
  uint4 o1 = make_uint4(vv[8]|(vv[9]<<16),  vv[10]|(vv[11]<<16),
                        vv[12]|(vv[13]<<16), vv[14]|(vv[15]<<16));
  *(uint4*)(dp + (size_t)c * R + rs)     = o0;
  *(uint4*)(dp + (size_t)c * R + rs + 8) = o1;
}

// ---------------- gate: logits (fp32 exact), softmax, top-2 -------------------
__global__ __launch_bounds__(256) void gate_kernel(
    const float* __restrict__ x, const float* __restrict__ wgate,
    float* __restrict__ logits_out, float* __restrict__ topk_p,
    int* __restrict__ flat_e, float* __restrict__ rl_out)
{
  __shared__ float xs[4][HDIM];
  const int w = threadIdx.x >> 6, lane = threadIdx.x & 63;
  const int tok = blockIdx.x * 4 + w;
  const float4* xr = (const float4*)(x + (size_t)tok * HDIM);
  float4* xd = (float4*)(&xs[w][0]);
#pragma unroll
  for (int j = 0; j < 4; ++j) xd[j * 64 + lane] = xr[j * 64 + lane];
  __syncthreads();
  float acc = 0.f;
#pragma unroll 8
  for (int h = 0; h < HDIM; ++h)
    acc = fmaf(xs[w][h], wgate[h * NEXP + lane], acc);
  logits_out[(size_t)tok * NEXP + lane] = acc;
  float m = acc;
#pragma unroll
  for (int d = 1; d < 64; d <<= 1) m = fmaxf(m, __shfl_xor(m, d));
  float p = expf(acc - m);
  float sum = p;
#pragma unroll
  for (int d = 1; d < 64; d <<= 1) sum += __shfl_xor(sum, d);
  float prob = p / sum;
  float v = prob; int idx = lane;
#pragma unroll
  for (int d = 1; d < 64; d <<= 1){
    float ov = __shfl_xor(v, d); int oi = __shfl_xor(idx, d);
    if (ov > v || (ov == v && oi < idx)){ v = ov; idx = oi; }
  }
  const int e1 = idx; const float p1 = v;
  v = (lane == e1) ? -1.f : prob; idx = lane;
#pragma unroll
  for (int d = 1; d < 64; d <<= 1){
    float ov = __shfl_xor(v, d); int oi = __shfl_xor(idx, d);
    if (ov > v || (ov == v && oi < idx)){ v = ov; idx = oi; }
  }
  if (lane == 0){
    flat_e[tok * 2]     = e1;  flat_e[tok * 2 + 1] = idx;
    topk_p[tok * 2]     = p1;  topk_p[tok * 2 + 1] = v;
  }
  if (tok == 0 && lane == 0) rl_out[0] = 0.f;
}

// ---------------- per-chunk expert histogram ---------------------------------
__global__ __launch_bounds__(256) void hist_kernel(const int* __restrict__ flat_e,
                                                   int* __restrict__ counts)
{
  __shared__ int hh[NEXP];
  const int t = threadIdx.x;
  if (t < NEXP) hh[t] = 0;
  __syncthreads();
  const int e = flat_e[blockIdx.x * 256 + t];
  atomicAdd(&hh[e], 1);
  __syncthreads();
  if (t < NEXP) counts[blockIdx.x * NEXP + t] = hh[t];
}

// ---------------- per-expert exclusive scan over chunks ----------------------
__global__ __launch_bounds__(256) void offsets_kernel(const int* __restrict__ counts,
                                                      int* __restrict__ offs,
                                                      int* __restrict__ etot)
{
  const int w = threadIdx.x >> 6, lane = threadIdx.x & 63;
  const int e = blockIdx.x * 4 + w;
  int v0 = counts[lane * NEXP + e];
  int v1 = counts[(64 + lane) * NEXP + e];
  int s0 = v0, s1 = v1;
#pragma unroll
  for (int d = 1; d < 64; d <<= 1){
    int n0 = __shfl_up(s0, d); if (lane >= d) s0 += n0;
    int n1 = __shfl_up(s1, d); if (lane >= d) s1 += n1;
  }
  const int tot0 = __shfl(s0, 63);
  offs[lane * NEXP + e]        = s0 - v0;
  offs[(64 + lane) * NEXP + e] = tot0 + s1 - v1;
  if (lane == 63) etot[e] = tot0 + s1;
}

// ---------------- ordered placement + slot map + cw --------------------------
__global__ __launch_bounds__(256) void place_kernel(
    const int* __restrict__ flat_e, const float* __restrict__ topk_p,
    const int* __restrict__ offs, int* __restrict__ entry_slot,
    int* __restrict__ token_of_slot, float* __restrict__ cw_out)
{
  __shared__ int es[256];
  __shared__ float wsh[256];
  const int t = threadIdx.x;
  const int i = blockIdx.x * 256 + t;
  const int e = flat_e[i];
  es[t] = e;
  __syncthreads();
  int local = 0;
  for (int j = 0; j < t; ++j) local += (es[j] == e);
  const int pos = offs[blockIdx.x * NEXP + e] + local;
  const bool valid = pos < CAPC;
  const int slot = e * CAPC + pos;
  entry_slot[i] = valid ? slot : -1;
  if (valid) token_of_slot[slot] = i >> 1;
  const float p = topk_p[i];
  wsh[t] = valid ? p : 0.f;
  __syncthreads();
  const float wme = wsh[t], wo = wsh[t ^ 1];
  cw_out[i] = wme / fmaxf(wme + wo, 1e-12f);
}

// ---------------- build dispatched A (bf16) ----------------------------------
__global__ __launch_bounds__(256) void adisp_kernel(
    const float* __restrict__ x, const int* __restrict__ token_of_slot,
    const int* __restrict__ etot, unsigned short* __restrict__ adisp)
{
  const int slot = blockIdx.x;
  const int e = slot / CAPC, c = slot - e * CAPC;
  int cnt = etot[e]; if (cnt > CAPC) cnt = CAPC;
  if (c >= cnt) return;
  const int tok = token_of_slot[slot];
  const int t = threadIdx.x;
  float4 v = ((const float4*)(x + (size_t)tok * HDIM))[t];
  ushort4 o; o.x = f2bf(v.x); o.y = f2bf(v.y); o.z = f2bf(v.z); o.w = f2bf(v.w);
  ((ushort4*)(adisp + (size_t)slot * HDIM))[t] = o;
}

// Tiles [rows][32 k] bf16, 64B rows = 4 x 16B units. Unit c: row=c>>2,
// jsrc=(c&3)^((row>>1)&3) (2-way bank alias = free). Staged gload_lds w16,
// linear LDS dest, pre-swizzled source. Fragment read: ds_read_b128 at
// row*32 + ((lane>>4)^((row>>1)&3))*8. (Verified data path, R4/R5.)

// ---------------- gemm1: fused g,u + SwiGLU; 3-stage pipeline ----------------
__global__ __launch_bounds__(256) void gemm1_kernel(
    const unsigned short* __restrict__ adisp,
    const unsigned short* __restrict__ wgu,   // [e][1024 merged n'][HDIM]
    unsigned short* __restrict__ hbuf)
{
  __shared__ unsigned short As[3][64 * 32];    // 4 KB each
  __shared__ unsigned short Bs[3][256 * 32];   // 16 KB each
  const int bb = blockIdx.x;
  const int lb = (bb & 7) * 320 + (bb >> 3);   // 2560 blocks, 2560%8==0
  const int e = lb / 40; const int r2 = lb - e * 40;
  const int nt = r2 / 10, mt = r2 - nt * 10;   // mt innermost: 10 share B panel
  const int t = threadIdx.x, w = t >> 6, lane = t & 63;
  const int wr = w >> 1, wc = w & 1;
  const size_t arow0 = (size_t)e * CAPC + (size_t)mt * 64;
  const unsigned short* abase = adisp + arow0 * HDIM;
  const unsigned short* bbase = wgu + ((size_t)e * 1024 + (size_t)nt * 256) * HDIM;

  // A: 256 units (1/thread); B: 1024 units (4/thread)
  int aoff, boff[4];
  {
    int c = t, row = c >> 2, jsrc = (c & 3) ^ ((row >> 1) & 3);
    aoff = row * HDIM + jsrc * 8;
  }
#pragma unroll
  for (int rr = 0; rr < 4; ++rr){
    int c = rr * 256 + t, row = c >> 2, jsrc = (c & 3) ^ ((row >> 1) & 3);
    boff[rr] = row * HDIM + jsrc * 8;
  }

  f32x4 accg[2][4], accu[2][4];
#pragma unroll
  for (int i = 0; i < 2; ++i)
#pragma unroll
    for (int j = 0; j < 4; ++j)
#pragma unroll
      for (int q = 0; q < 4; ++q){ accg[i][j][q] = 0.f; accu[i][j][q] = 0.f; }

  auto stage = [&](int buf, int kb){
    gload_lds16(abase + aoff + kb, &As[buf][(w * 64) * 8]);
#pragma unroll
    for (int rr = 0; rr < 4; ++rr)
      gload_lds16(bbase + boff[rr] + kb, &Bs[buf][((rr * 256) + w * 64) * 8]);
  };

  constexpr int NK = HDIM / 32;   // 32 steps
  stage(0, 0);
  stage(1, 32);                   // 12 outstanding / wave
  for (int ti = 0; ti < NK; ++ti){
    const int cur = ti % 3;
    if (ti < NK - 1) asm volatile("s_waitcnt vmcnt(6)" ::: "memory");
    else             asm volatile("s_waitcnt vmcnt(0)" ::: "memory");
    __builtin_amdgcn_s_barrier();
    __builtin_amdgcn_sched_barrier(0);
    if (ti + 2 < NK) stage((ti + 2) % 3, (ti + 2) * 32);   // distance-2 prefetch

    const int j8 = lane >> 4;
    bf16x8 af[2], bg[4], bu[4];
#pragma unroll
    for (int m = 0; m < 2; ++m){
      int row = wr * 32 + m * 16 + (lane & 15);
      af[m] = *(const bf16x8*)&As[cur][row * 32 + ((j8 ^ ((row >> 1) & 3)) * 8)];
    }
#pragma unroll
    for (int n = 0; n < 4; ++n){
      int brow = wc * 64 + n * 16 + (lane & 15);
      bg[n] = *(const bf16x8*)&Bs[cur][brow * 32 + ((j8 ^ ((brow >> 1) & 3)) * 8)];
      int urow = brow + 128;
      bu[n] = *(const bf16x8*)&Bs[cur][urow * 32 + ((j8 ^ ((urow >> 1) & 3)) * 8)];
    }
    __builtin_amdgcn_s_setprio(1);
#pragma unroll
    for (int m = 0; m < 2; ++m)
#pragma unroll
      for (int n = 0; n < 4; ++n){
        accg[m][n] = __builtin_amdgcn_mfma_f32_16x16x32_bf16(af[m], bg[n], accg[m][n], 0, 0, 0);
        accu[m][n] = __builtin_amdgcn_mfma_f32_16x16x32_bf16(af[m], bu[n], accu[m][n], 0, 0, 0);
      }
    __builtin_amdgcn_s_setprio(0);
  }
  // epilogue: h = silu(g)*u -> bf16
#pragma unroll
  for (int m = 0; m < 2; ++m)
#pragma unroll
    for (int n = 0; n < 4; ++n)
#pragma unroll
      for (int q = 0; q < 4; ++q){
        int row = wr * 32 + m * 16 + (lane >> 4) * 4 + q;
        int col = nt * 128 + wc * 64 + n * 16 + (lane & 15);
        float gv = accg[m][n][q], uv = accu[m][n][q];
        float hv = gv / (1.f + expf(-gv)) * uv;
        hbuf[(arow0 + row) * IDIM + col] = f2bf(hv);
      }
}

// ---------------- gemm2: eo = h * Wd (bf16 out); 3-stage pipeline ------------
__global__ __launch_bounds__(256) void gemm2_kernel(
    const unsigned short* __restrict__ hbuf,
    const unsigned short* __restrict__ wdt,   // [e][HDIM][IDIM]
    unsigned short* __restrict__ eo)
{
  __shared__ unsigned short As[3][128 * 32];   // 8 KB each
  __shared__ unsigned short Bs[3][128 * 32];   // 8 KB each
  const int bb = blockIdx.x;
  const int lb = (bb & 7) * 320 + (bb >> 3);   // 2560 blocks
  const int e = lb / 40; const int r2 = lb - e * 40;
  const int nt = r2 / 5, mt = r2 - nt * 5;     // mt innermost: 5 share B panel
  const int t = threadIdx.x, w = t >> 6, lane = t & 63;
  const int wr = w >> 1, wc = w & 1;
  const size_t arow0 = (size_t)e * CAPC + (size_t)mt * 128;
  const unsigned short* abase = hbuf + arow0 * IDIM;
  const unsigned short* bbase = wdt + ((size_t)e * HDIM + (size_t)nt * 128) * IDIM;

  int aoff[2], boff[2];
#pragma unroll
  for (int rr = 0; rr < 2; ++rr){
    int c = rr * 256 + t, row = c >> 2, jsrc = (c & 3) ^ ((row >> 1) & 3);
    aoff[rr] = row * IDIM + jsrc * 8;
    boff[rr] = row * IDIM + jsrc * 8;
  }

  f32x4 acc[4][4];
#pragma unroll
  for (int i = 0; i < 4; ++i)
#pragma unroll
    for (int j = 0; j < 4; ++j)
#pragma unroll
      for (int q = 0; q < 4; ++q) acc[i][j][q] = 0.f;

  auto stage = [&](int buf, int kb){
#pragma unroll
    for (int rr = 0; rr < 2; ++rr)
      gload_lds16(abase + aoff[rr] + kb, &As[buf][((rr * 256) + w * 64) * 8]);
#pragma unroll
    for (int rr = 0; rr < 2; ++rr)
      gload_lds16(bbase + boff[rr] + kb, &Bs[buf][((rr * 256) + w * 64) * 8]);
  };

  constexpr int NK = IDIM / 32;   // 16 steps
  stage(0, 0);
  stage(1, 32);                   // 8 outstanding / wave
  for (int ti = 0; ti < NK; ++ti){
    const int cur = ti % 3;
    if (ti < NK - 1) asm volatile("s_waitcnt vmcnt(4)" ::: "memory");
    else             asm volatile("s_waitcnt vmcnt(0)" ::: "memory");
    __builtin_amdgcn_s_barrier();
    __builtin_amdgcn_sched_barrier(0);
    if (ti + 2 < NK) stage((ti + 2) % 3, (ti + 2) * 32);

    const int j8 = lane >> 4;
    bf16x8 af[4], bfr[4];
#pragma unroll
    for (int m = 0; m < 4; ++m){
      int row = wr * 64 + m * 16 + (lane & 15);
      af[m] = *(const bf16x8*)&As[cur][row * 32 + ((j8 ^ ((row >> 1) & 3)) * 8)];
    }
#pragma unroll
    for (int n = 0; n < 4; ++n){
      int brow = wc * 64 + n * 16 + (lane & 15);
      bfr[n] = *(const bf16x8*)&Bs[cur][brow * 32 + ((j8 ^ ((brow >> 1) & 3)) * 8)];
    }
    __builtin_amdgcn_s_setprio(1);
#pragma unroll
    for (int m = 0; m < 4; ++m)
#pragma unroll
      for (int n = 0; n < 4; ++n)
        acc[m][n] = __builtin_amdgcn_mfma_f32_16x16x32_bf16(af[m], bfr[n], acc[m][n], 0, 0, 0);
    __builtin_amdgcn_s_setprio(0);
  }
#pragma unroll
  for (int m = 0; m < 4; ++m)
#pragma unroll
    for (int n = 0; n < 4; ++n)
#pragma unroll
      for (int q = 0; q < 4; ++q){
        int row = wr * 64 + m * 16 + (lane >> 4) * 4 + q;
        int col = nt * 128 + wc * 64 + n * 16 + (lane & 15);
        eo[(arow0 + row) * HDIM + col] = f2bf(acc[m][n][q]);
      }
}

// ---------------- combine: out[s] = sum_k cw[s,k] * eo[slot(s,k)] ------------
__global__ __launch_bounds__(256) void combine_kernel(
    const unsigned short* __restrict__ eo, const int* __restrict__ entry_slot,
    const float* __restrict__ cw, float* __restrict__ out)
{
  const int s = blockIdx.x, t = threadIdx.x;
  const int s0 = entry_slot[2 * s], s1 = entry_slot[2 * s + 1];
  const float w0 = cw[2 * s], w1 = cw[2 * s + 1];
  const int c = t * 4;
  float r0 = 0.f, r1 = 0.f, r2 = 0.f, r3 = 0.f;
  if (s0 >= 0){
    ushort4 vq = *(const ushort4*)&eo[(size_t)s0 * HDIM + c];
    r0 += w0 * bf2f(vq.x); r1 += w0 * bf2f(vq.y); r2 += w0 * bf2f(vq.z); r3 += w0 * bf2f(vq.w);
  }
  if (s1 >= 0){
    ushort4 vq = *(const ushort4*)&eo[(size_t)s1 * HDIM + c];
    r0 += w1 * bf2f(vq.x); r1 += w1 * bf2f(vq.y); r2 += w1 * bf2f(vq.z); r3 += w1 * bf2f(vq.w);
  }
  ((float4*)(out + (size_t)s * HDIM))[t] = make_float4(r0, r1, r2, r3);
}

extern "C" void kernel_launch(void* const* d_in, const int* in_sizes, int n_in,
                              void* d_out, int out_size, void* d_ws, size_t ws_size,
                              hipStream_t stream) {
  (void)in_sizes; (void)n_in; (void)out_size; (void)ws_size;
  const float* x     = (const float*)d_in[0];
  const float* wgate = (const float*)d_in[1];
  const float* wg    = (const float*)d_in[2];
  const float* wu    = (const float*)d_in[3];
  const float* wd    = (const float*)d_in[4];

  float* out        = (float*)d_out;                         // [S,H]
  float* cw_out     = out + (size_t)S_TOK * HDIM;            // [S,2]
  float* rl_out     = cw_out + (size_t)S_TOK * 2;            // [1]
  float* logits_out = rl_out + 1;                            // [S,64]

  char* w8 = (char*)d_ws;
  size_t off = 0;
  auto alloc = [&](size_t bytes){ size_t r = off; off += (bytes + 255) & ~(size_t)255; return r; };
  int*   flat_e_ws        = (int*)  (w8 + alloc((size_t)32768 * 4));
  float* topk_p_ws        = (float*)(w8 + alloc((size_t)32768 * 4));
  int*   counts_ws        = (int*)  (w8 + alloc((size_t)NCHUNK * NEXP * 4));
  int*   offs_ws          = (int*)  (w8 + alloc((size_t)NCHUNK * NEXP * 4));
  int*   etot_ws          = (int*)  (w8 + alloc((size_t)NEXP * 4));
  int*   entry_slot_ws    = (int*)  (w8 + alloc((size_t)32768 * 4));
  int*   token_of_slot_ws = (int*)  (w8 + alloc((size_t)NEXP * CAPC * 4));
  unsigned short* hbuf_ws = (unsigned short*)(w8 + alloc((size_t)NEXP * CAPC * IDIM * 2));
  unsigned short* adisp_ws= (unsigned short*)(w8 + alloc((size_t)NEXP * CAPC * HDIM * 2));
  unsigned short* wgu_ws  = (unsigned short*)(w8 + alloc((size_t)NEXP * 2 * IDIM * HDIM * 2));
  unsigned short* eo_ws   = adisp_ws;   // alias: adisp dead after gemm1
  unsigned short* wdt_ws  = wgu_ws;     // alias: wgu dead after gemm1

  gate_kernel   <<<S_TOK / 4, 256, 0, stream>>>(x, wgate, logits_out, topk_p_ws, flat_e_ws, rl_out);
  hist_kernel   <<<NCHUNK,    256, 0, stream>>>(flat_e_ws, counts_ws);
  offsets_kernel<<<16,        256, 0, stream>>>(counts_ws, offs_ws, etot_ws);
  place_kernel  <<<NCHUNK,    256, 0, stream>>>(flat_e_ws, topk_p_ws, offs_ws,
                                                entry_slot_ws, token_of_slot_ws, cw_out);
  adisp_kernel  <<<NEXP * CAPC, 256, 0, stream>>>(x, token_of_slot_ws, etot_ws, adisp_ws);
  // merged transpose-convert: wg -> rows (n>>7)*256+(n&127), wu -> +128
  wcvtT_kernel  <<<NEXP * 128, 256, 0, stream>>>(wg, wgu_ws, HDIM, IDIM, 256, 0,
                                                 (size_t)1024 * HDIM);
  wcvtT_kernel  <<<NEXP * 128, 256, 0, stream>>>(wu, wgu_ws, HDIM, IDIM, 256, 128,
                                                 (size_t)1024 * HDIM);
  gemm1_kernel  <<<NEXP * 40, 256, 0, stream>>>(adisp_ws, wgu_ws, hbuf_ws);
  wcvtT_kernel  <<<NEXP * 128, 256, 0, stream>>>(wd, wdt_ws, IDIM, HDIM, 128, 0,
                                                 (size_t)HDIM * IDIM);
  gemm2_kernel  <<<NEXP * 40, 256, 0, stream>>>(hbuf_ws, wdt_ws, eo_ws);
  combine_kernel<<<S_TOK,     256, 0, stream>>>(eo_ws, entry_slot_ws, cw_out, out);
}

// Round 8
// 566.181 us; speedup vs baseline: 1.0913x; 1.0073x over previous
//
// Ernie4.5 MoE MLP — MI355X gfx950
// R8: arithmetic-intensity fix. Both GEMMs: 512 thr / 8 waves (2x4), block tile
//     128x512, wave 64x128 (4m x 8n 16x16x32, acc=128 VGPR), BK=32, 3-stage
//     counted-vmcnt pipeline (one barrier/iter, vmcnt(5) steady state).
//     Per K-step: 4.2 MFLOP vs ~136KB LDS -> MfmaUtil ceiling 65-97% (was 37%).
//     wg|wu merged at 16-col interleave -> SwiGLU fully in-lane, single B stream.
// ws peak ~250 MB. eo aliases adisp; wdt aliases wgu (dead after gemm1).
#include <hip/hip_runtime.h>
#include <hip/hip_bf16.h>

constexpr int S_TOK = 16384;
constexpr int HDIM  = 1024;
constexpr int IDIM  = 512;
constexpr int NEXP  = 64;
constexpr int CAPC  = 640;
constexpr int NCHUNK = 128;   // 32768 routing entries / 256

typedef __attribute__((ext_vector_type(8))) short bf16x8;
typedef __attribute__((ext_vector_type(4))) float f32x4;

__device__ __forceinline__ float bf2f(unsigned short u){
  return __uint_as_float(((unsigned)u) << 16);
}
__device__ __forceinline__ unsigned short f2bf(float f){   // RNE bf16 (inputs finite)
  unsigned u = __float_as_uint(f);
  return (unsigned short)((u + 0x7fffu + ((u >> 16) & 1u)) >> 16);
}
__device__ __forceinline__ void gload_lds16(const void* g, void* l){
  __builtin_amdgcn_global_load_lds((const __attribute__((address_space(1))) unsigned*)g,
                                   (__attribute__((address_space(3))) unsigned*)l, 16, 0, 0);
}

// ---------------- weight fp32 [R][C] -> bf16 transposed, column remap --------
// dst row n' = (gc>>4)*ostep + (gc&15) + oofs ; dst layout [e][*][R]
__global__ __launch_bounds__(256) void wcvtT_kernel(const float* __restrict__ src,
                                                    unsigned short* __restrict__ dst,
                                                    int R, int C, int ostep, int oofs,
                                                    size_t dexp)
{
  __shared__ unsigned short ls[64 * 72];     // [r][c], stride 72 (pad)
  const int tilesC = C >> 6;
  const int tpe = (R >> 6) * tilesC;
  const int b = blockIdx.x;
  const int e = b / tpe, rem = b - e * tpe;
  const int r0 = (rem / tilesC) * 64, c0 = (rem % tilesC) * 64;
  const float* sp = src + (size_t)e * R * C + (size_t)r0 * C + c0;
  const int t = threadIdx.x;
  const int rsub = t >> 4, cs = (t & 15) * 4;
#pragma unroll
  for (int q = 0; q < 4; ++q){
    int r = rsub * 4 + q;
    float4 v = *(const float4*)(sp + (size_t)r * C + cs);
    unsigned short* lp = &ls[r * 72 + cs];
    lp[0] = f2bf(v.x); lp[1] = f2bf(v.y); lp[2] = f2bf(v.z); lp[3] = f2bf(v.w);
  }
  __syncthreads();
  const int c = t >> 2, rs = (t & 3) * 16;
  unsigned vv[16];
#pragma unroll
  for (int j = 0; j < 16; ++j) vv[j] = ls[(rs + j) * 72 + c];
  uint4 o0 = make_uint4(vv[0]|(vv[1]<<16),  vv[2]|(vv[3]<<16),
                        vv[4]|(vv[5]<<16),  vv[6]|(vv[7]<<16));
  uint4 o1 = make_uint4(vv[8]|(vv[9]<<16),  vv[10]|(vv[11]<<16),
                        vv[12]|(vv[13]<<16), vv[14]|(vv[15]<<16));
  const int gc = c0 + c;
  const int np = (gc >> 4) * ostep + (gc & 15) + oofs;
  unsigned short* dq = dst + (size_t)e * dexp + (size_t)np * R + r0;
  *(uint4*)(dq + rs)     = o0;
  *(uint4*)(dq + rs + 8) = o1;
}

// ---------------- gate: logits (fp32 exact), softmax, top-2 -------------------
__global__ __launch_bounds__(256) void gate_kernel(
    const float* __restrict__ x, const float* __restrict__ wgate,
    float* __restrict__ logits_out, float* __restrict__ topk_p,
    int* __restrict__ flat_e, float* __restrict__ rl_out)
{
  __shared__ float xs[4][HDIM];
  const int w = threadIdx.x >> 6, lane = threadIdx.x & 63;
  const int tok = blockIdx.x * 4 + w;
  const float4* xr = (const float4*)(x + (size_t)tok * HDIM);
  float4* xd = (float4*)(&xs[w][0]);
#pragma unroll
  for (int j = 0; j < 4; ++j) xd[j * 64 + lane] = xr[j * 64 + lane];
  __syncthreads();
  float acc = 0.f;
#pragma unroll 8
  for (int h = 0; h < HDIM; ++h)
    acc = fmaf(xs[w][h], wgate[h * NEXP + lane], acc);
  logits_out[(size_t)tok * NEXP + lane] = acc;
  float m = acc;
#pragma unroll
  for (int d = 1; d < 64; d <<= 1) m = fmaxf(m, __shfl_xor(m, d));
  float p = expf(acc - m);
  float sum = p;
#pragma unroll
  for (int d = 1; d < 64; d <<= 1) sum += __shfl_xor(sum, d);
  float prob = p / sum;
  float v = prob; int idx = lane;
#pragma unroll
  for (int d = 1; d < 64; d <<= 1){
    float ov = __shfl_xor(v, d); int oi = __shfl_xor(idx, d);
    if (ov > v || (ov == v && oi < idx)){ v = ov; idx = oi; }
  }
  const int e1 = idx; const float p1 = v;
  v = (lane == e1) ? -1.f : prob; idx = lane;
#pragma unroll
  for (int d = 1; d < 64; d <<= 1){
    float ov = __shfl_xor(v, d); int oi = __shfl_xor(idx, d);
    if (ov > v || (ov == v && oi < idx)){ v = ov; idx = oi; }
  }
  if (lane == 0){
    flat_e[tok * 2]     = e1;  flat_e[tok * 2 + 1] = idx;
    topk_p[tok * 2]     = p1;  topk_p[tok * 2 + 1] = v;
  }
  if (tok == 0 && lane == 0) rl_out[0] = 0.f;
}

// ---------------- per-chunk expert histogram ---------------------------------
__global__ __launch_bounds__(256) void hist_kernel(const int* __restrict__ flat_e,
                                                   int* __restrict__ counts)
{
  __shared__ int hh[NEXP];
  const int t = threadIdx.x;
  if (t < NEXP) hh[t] = 0;
  __syncthreads();
  const int e = flat_e[blockIdx.x * 256 + t];
  atomicAdd(&hh[e], 1);
  __syncthreads();
  if (t < NEXP) counts[blockIdx.x * NEXP + t] = hh[t];
}

// ---------------- per-expert exclusive scan over chunks ----------------------
__global__ __launch_bounds__(256) void offsets_kernel(const int* __restrict__ counts,
                                                      int* __restrict__ offs,
                                                      int* __restrict__ etot)
{
  const int w = threadIdx.x >> 6, lane = threadIdx.x & 63;
  const int e = blockIdx.x * 4 + w;
  int v0 = counts[lane * NEXP + e];
  int v1 = counts[(64 + lane) * NEXP + e];
  int s0 = v0, s1 = v1;
#pragma unroll
  for (int d = 1; d < 64; d <<= 1){
    int n0 = __shfl_up(s0, d); if (lane >= d) s0 += n0;
    int n1 = __shfl_up(s1, d); if (lane >= d) s1 += n1;
  }
  const int tot0 = __shfl(s0, 63);
  offs[lane * NEXP + e]        = s0 - v0;
  offs[(64 + lane) * NEXP + e] = tot0 + s1 - v1;
  if (lane == 63) etot[e] = tot0 + s1;
}

// ---------------- ordered placement + slot map + cw --------------------------
__global__ __launch_bounds__(256) void place_kernel(
    const int* __restrict__ flat_e, const float* __restrict__ topk_p,
    const int* __restrict__ offs, int* __restrict__ entry_slot,
    int* __restrict__ token_of_slot, float* __restrict__ cw_out)
{
  __shared__ int es[256];
  __shared__ float wsh[256];
  const int t = threadIdx.x;
  const int i = blockIdx.x * 256 + t;
  const int e = flat_e[i];
  es[t] = e;
  __syncthreads();
  int local = 0;
  for (int j = 0; j < t; ++j) local += (es[j] == e);
  const int pos = offs[blockIdx.x * NEXP + e] + local;
  const bool valid = pos < CAPC;
  const int slot = e * CAPC + pos;
  entry_slot[i] = valid ? slot : -1;
  if (valid) token_of_slot[slot] = i >> 1;
  const float p = topk_p[i];
  wsh[t] = valid ? p : 0.f;
  __syncthreads();
  const float wme = wsh[t], wo = wsh[t ^ 1];
  cw_out[i] = wme / fmaxf(wme + wo, 1e-12f);
}

// ---------------- build dispatched A (bf16) ----------------------------------
__global__ __launch_bounds__(256) void adisp_kernel(
    const float* __restrict__ x, const int* __restrict__ token_of_slot,
    const int* __restrict__ etot, unsigned short* __restrict__ adisp)
{
  const int slot = blockIdx.x;
  const int e = slot / CAPC, c = slot - e * CAPC;
  int cnt = etot[e]; if (cnt > CAPC) cnt = CAPC;
  if (c >= cnt) return;
  const int tok = token_of_slot[slot];
  const int t = threadIdx.x;
  float4 v = ((const float4*)(x + (size_t)tok * HDIM))[t];
  ushort4 o; o.x = f2bf(v.x); o.y = f2bf(v.y); o.z = f2bf(v.z); o.w = f2bf(v.w);
  ((ushort4*)(adisp + (size_t)slot * HDIM))[t] = o;
}

// Tiles [rows][32 k] bf16, 64B rows = 4 x 16B units. Unit c: row=c>>2,
// jsrc=(c&3)^((row>>1)&3) (2-way bank alias = free). Staged gload_lds w16,
// linear LDS dest, pre-swizzled source. Fragment: ds_read_b128 at
// row*32 + ((lane>>4)^((row>>1)&3))*8. (Verified data path, R4/R5/R7.)

// ---------------- gemm1: 128x512-merged tile, SwiGLU in-lane -----------------
__global__ __launch_bounds__(512, 2) void gemm1_kernel(
    const unsigned short* __restrict__ adisp,
    const unsigned short* __restrict__ wgu,   // [e][1024 merged][HDIM]
    unsigned short* __restrict__ hbuf)
{
  __shared__ unsigned short As[3][128 * 32];   // 8 KB each
  __shared__ unsigned short Bs[3][512 * 32];   // 32 KB each
  const int bb = blockIdx.x;
  const int lb = (bb & 7) * 80 + (bb >> 3);    // 640 blocks, 640%8==0
  const int e = lb / 10; const int r2 = lb - e * 10;
  const int nt = r2 / 5, mt = r2 - nt * 5;     // mt innermost: 5 share B panel
  const int t = threadIdx.x, w = t >> 6, lane = t & 63;
  const int wr = w >> 2, wc = w & 3;           // 2 x 4 wave grid
  const size_t arow0 = (size_t)e * CAPC + (size_t)mt * 128;
  const unsigned short* abase = adisp + arow0 * HDIM;
  const unsigned short* bbase = wgu + ((size_t)e * 1024 + (size_t)nt * 512) * HDIM;

  int aoff, boff[4];
  { int c = t, row = c >> 2, jsrc = (c & 3) ^ ((row >> 1) & 3);
    aoff = row * HDIM + jsrc * 8; }
#pragma unroll
  for (int rr = 0; rr < 4; ++rr){
    int c = rr * 512 + t, row = c >> 2, jsrc = (c & 3) ^ ((row >> 1) & 3);
    boff[rr] = row * HDIM + jsrc * 8;
  }

  f32x4 acc[4][8];
#pragma unroll
  for (int i = 0; i < 4; ++i)
#pragma unroll
    for (int j = 0; j < 8; ++j)
#pragma unroll
      for (int q = 0; q < 4; ++q) acc[i][j][q] = 0.f;

  auto stage = [&](int buf, int kb){
    gload_lds16(abase + aoff + kb, &As[buf][(w * 64) * 8]);
#pragma unroll
    for (int rr = 0; rr < 4; ++rr)
      gload_lds16(bbase + boff[rr] + kb, &Bs[buf][(rr * 512 + w * 64) * 8]);
  };

  constexpr int NK = HDIM / 32;   // 32 steps
  stage(0, 0);
  stage(1, 32);                    // 10 loads outstanding / wave
  int cur = 0;
  for (int ti = 0; ti < NK; ++ti){
    if (ti < NK - 1) asm volatile("s_waitcnt vmcnt(5)" ::: "memory");  // tile ti landed
    else             asm volatile("s_waitcnt vmcnt(0)" ::: "memory");
    __builtin_amdgcn_s_barrier();
    __builtin_amdgcn_sched_barrier(0);
    if (ti + 2 < NK){
      int pf = cur + 2; if (pf >= 3) pf -= 3;
      stage(pf, (ti + 2) * 32);
    }

    const int j8 = lane >> 4;
    bf16x8 af[4], bfr[8];
#pragma unroll
    for (int m = 0; m < 4; ++m){
      int row = wr * 64 + m * 16 + (lane & 15);
      af[m] = *(const bf16x8*)&As[cur][row * 32 + ((j8 ^ ((row >> 1) & 3)) * 8)];
    }
#pragma unroll
    for (int n = 0; n < 8; ++n){
      int brow = wc * 128 + n * 16 + (lane & 15);
      bfr[n] = *(const bf16x8*)&Bs[cur][brow * 32 + ((j8 ^ ((brow >> 1) & 3)) * 8)];
    }
    __builtin_amdgcn_s_setprio(1);
#pragma unroll
    for (int m = 0; m < 4; ++m)
#pragma unroll
      for (int n = 0; n < 8; ++n)
        acc[m][n] = __builtin_amdgcn_mfma_f32_16x16x32_bf16(af[m], bfr[n], acc[m][n], 0, 0, 0);
    __builtin_amdgcn_s_setprio(0);
    cur = (cur == 2) ? 0 : cur + 1;
  }
  // epilogue: merged cols interleave g/u at 16: acc[m][2j]=g, acc[m][2j+1]=u
#pragma unroll
  for (int m = 0; m < 4; ++m)
#pragma unroll
    for (int j = 0; j < 4; ++j)
#pragma unroll
      for (int q = 0; q < 4; ++q){
        int row = wr * 64 + m * 16 + (lane >> 4) * 4 + q;
        int col = nt * 256 + wc * 64 + j * 16 + (lane & 15);
        float gv = acc[m][2 * j][q], uv = acc[m][2 * j + 1][q];
        float hv = gv / (1.f + expf(-gv)) * uv;
        hbuf[(arow0 + row) * IDIM + col] = f2bf(hv);
      }
}

// ---------------- gemm2: eo = h * Wd; 128x512 tile ---------------------------
__global__ __launch_bounds__(512, 2) void gemm2_kernel(
    const unsigned short* __restrict__ hbuf,
    const unsigned short* __restrict__ wdt,   // [e][HDIM][IDIM]
    unsigned short* __restrict__ eo)
{
  __shared__ unsigned short As[3][128 * 32];
  __shared__ unsigned short Bs[3][512 * 32];
  const int bb = blockIdx.x;
  const int lb = (bb & 7) * 80 + (bb >> 3);    // 640 blocks
  const int e = lb / 10; const int r2 = lb - e * 10;
  const int nt = r2 / 5, mt = r2 - nt * 5;
  const int t = threadIdx.x, w = t >> 6, lane = t & 63;
  const int wr = w >> 2, wc = w & 3;
  const size_t arow0 = (size_t)e * CAPC + (size_t)mt * 128;
  const unsigned short* abase = hbuf + arow0 * IDIM;
  const unsigned short* bbase = wdt + ((size_t)e * HDIM + (size_t)nt * 512) * IDIM;

  int aoff, boff[4];
  { int c = t, row = c >> 2, jsrc = (c & 3) ^ ((row >> 1) & 3);
    aoff = row * IDIM + jsrc * 8; }
#pragma unroll
  for (int rr = 0; rr < 4; ++rr){
    int c = rr * 512 + t, row = c >> 2, jsrc = (c & 3) ^ ((row >> 1) & 3);
    boff[rr] = row * IDIM + jsrc * 8;
  }

  f32x4 acc[4][8];
#pragma unroll
  for (int i = 0; i < 4; ++i)
#pragma unroll
    for (int j = 0; j < 8; ++j)
#pragma unroll
      for (int q = 0; q < 4; ++q) acc[i][j][q] = 0.f;

  auto stage = [&](int buf, int kb){
    gload_lds16(abase + aoff + kb, &As[buf][(w * 64) * 8]);
#pragma unroll
    for (int rr = 0; rr < 4; ++rr)
      gload_lds16(bbase + boff[rr] + kb, &Bs[buf][(rr * 512 + w * 64) * 8]);
  };

  constexpr int NK = IDIM / 32;   // 16 steps
  stage(0, 0);
  stage(1, 32);
  int cur = 0;
  for (int ti = 0; ti < NK; ++ti){
    if (ti < NK - 1) asm volatile("s_waitcnt vmcnt(5)" ::: "memory");
    else             asm volatile("s_waitcnt vmcnt(0)" ::: "memory");
    __builtin_amdgcn_s_barrier();
    __builtin_amdgcn_sched_barrier(0);
    if (ti + 2 < NK){
      int pf = cur + 2; if (pf >= 3) pf -= 3;
      stage(pf, (ti + 2) * 32);
    }

    const int j8 = lane >> 4;
    bf16x8 af[4], bfr[8];
#pragma unroll
    for (int m = 0; m < 4; ++m){
      int row = wr * 64 + m * 16 + (lane & 15);
      af[m] = *(const bf16x8*)&As[cur][row * 32 + ((j8 ^ ((row >> 1) & 3)) * 8)];
    }
#pragma unroll
    for (int n = 0; n < 8; ++n){
      int brow = wc * 128 + n * 16 + (lane & 15);
      bfr[n] = *(const bf16x8*)&Bs[cur][brow * 32 + ((j8 ^ ((brow >> 1) & 3)) * 8)];
    }
    __builtin_amdgcn_s_setprio(1);
#pragma unroll
    for (int m = 0; m < 4; ++m)
#pragma unroll
      for (int n = 0; n < 8; ++n)
        acc[m][n] = __builtin_amdgcn_mfma_f32_16x16x32_bf16(af[m], bfr[n], acc[m][n], 0, 0, 0);
    __builtin_amdgcn_s_setprio(0);
    cur = (cur == 2) ? 0 : cur + 1;
  }
#pragma unroll
  for (int m = 0; m < 4; ++m)
#pragma unroll
    for (int n = 0; n < 8; ++n)
#pragma unroll
      for (int q = 0; q < 4; ++q){
        int row = wr * 64 + m * 16 + (lane >> 4) * 4 + q;
        int col = nt * 512 + wc * 128 + n * 16 + (lane & 15);
        eo[(arow0 + row) * HDIM + col] = f2bf(acc[m][n][q]);
      }
}

// ---------------- combine: out[s] = sum_k cw[s,k] * eo[slot(s,k)] ------------
__global__ __launch_bounds__(256) void combine_kernel(
    const unsigned short* __restrict__ eo, const int* __restrict__ entry_slot,
    const float* __restrict__ cw, float* __restrict__ out)
{
  const int s = blockIdx.x, t = threadIdx.x;
  const int s0 = entry_slot[2 * s], s1 = entry_slot[2 * s + 1];
  const float w0 = cw[2 * s], w1 = cw[2 * s + 1];
  const int c = t * 4;
  float r0 = 0.f, r1 = 0.f, r2 = 0.f, r3 = 0.f;
  if (s0 >= 0){
    ushort4 vq = *(const ushort4*)&eo[(size_t)s0 * HDIM + c];
    r0 += w0 * bf2f(vq.x); r1 += w0 * bf2f(vq.y); r2 += w0 * bf2f(vq.z); r3 += w0 * bf2f(vq.w);
  }
  if (s1 >= 0){
    ushort4 vq = *(const ushort4*)&eo[(size_t)s1 * HDIM + c];
    r0 += w1 * bf2f(vq.x); r1 += w1 * bf2f(vq.y); r2 += w1 * bf2f(vq.z); r3 += w1 * bf2f(vq.w);
  }
  ((float4*)(out + (size_t)s * HDIM))[t] = make_float4(r0, r1, r2, r3);
}

extern "C" void kernel_launch(void* const* d_in, const int* in_sizes, int n_in,
                              void* d_out, int out_size, void* d_ws, size_t ws_size,
                              hipStream_t stream) {
  (void)in_sizes; (void)n_in; (void)out_size; (void)ws_size;
  const float* x     = (const float*)d_in[0];
  const float* wgate = (const float*)d_in[1];
  const float* wg    = (const float*)d_in[2];
  const float* wu    = (const float*)d_in[3];
  const float* wd    = (const float*)d_in[4];

  float* out        = (float*)d_out;                         // [S,H]
  float* cw_out     = out + (size_t)S_TOK * HDIM;            // [S,2]
  float* rl_out     = cw_out + (size_t)S_TOK * 2;            // [1]
  float* logits_out = rl_out + 1;                            // [S,64]

  char* w8 = (char*)d_ws;
  size_t off = 0;
  auto alloc = [&](size_t bytes){ size_t r = off; off += (bytes + 255) & ~(size_t)255; return r; };
  int*   flat_e_ws        = (int*)  (w8 + alloc((size_t)32768 * 4));
  float* topk_p_ws        = (float*)(w8 + alloc((size_t)32768 * 4));
  int*   counts_ws        = (int*)  (w8 + alloc((size_t)NCHUNK * NEXP * 4));
  int*   offs_ws          = (int*)  (w8 + alloc((size_t)NCHUNK * NEXP * 4));
  int*   etot_ws          = (int*)  (w8 + alloc((size_t)NEXP * 4));
  int*   entry_slot_ws    = (int*)  (w8 + alloc((size_t)32768 * 4));
  int*   token_of_slot_ws = (int*)  (w8 + alloc((size_t)NEXP * CAPC * 4));
  unsigned short* hbuf_ws = (unsigned short*)(w8 + alloc((size_t)NEXP * CAPC * IDIM * 2));
  unsigned short* adisp_ws= (unsigned short*)(w8 + alloc((size_t)NEXP * CAPC * HDIM * 2));
  unsigned short* wgu_ws  = (unsigned short*)(w8 + alloc((size_t)NEXP * 2 * IDIM * HDIM * 2));
  unsigned short* eo_ws   = adisp_ws;   // alias: adisp dead after gemm1
  unsigned short* wdt_ws  = wgu_ws;     // alias: wgu dead after gemm1

  gate_kernel   <<<S_TOK / 4, 256, 0, stream>>>(x, wgate, logits_out, topk_p_ws, flat_e_ws, rl_out);
  hist_kernel   <<<NCHUNK,    256, 0, stream>>>(flat_e_ws, counts_ws);
  offsets_kernel<<<16,        256, 0, stream>>>(counts_ws, offs_ws, etot_ws);
  place_kernel  <<<NCHUNK,    256, 0, stream>>>(flat_e_ws, topk_p_ws, offs_ws,
                                                entry_slot_ws, token_of_slot_ws, cw_out);
  adisp_kernel  <<<NEXP * CAPC, 256, 0, stream>>>(x, token_of_slot_ws, etot_ws, adisp_ws);
  // merged 16-col interleave: g -> (n>>4)*32+(n&15), u -> +16; wd identity
  wcvtT_kernel  <<<NEXP * 128, 256, 0, stream>>>(wg, wgu_ws, HDIM, IDIM, 32, 0,
                                                 (size_t)1024 * HDIM);
  wcvtT_kernel  <<<NEXP * 128, 256, 0, stream>>>(wu, wgu_ws, HDIM, IDIM, 32, 16,
                                                 (size_t)1024 * HDIM);
  gemm1_kernel  <<<NEXP * 10, 512, 0, stream>>>(adisp_ws, wgu_ws, hbuf_ws);
  wcvtT_kernel  <<<NEXP * 128, 256, 0, stream>>>(wd, wdt_ws, IDIM, HDIM, 16, 0,
                                                 (size_t)HDIM * IDIM);
  gemm2_kernel  <<<NEXP * 10, 512, 0, stream>>>(hbuf_ws, wdt_ws, eo_ws);
  combine_kernel<<<S_TOK,     256, 0, stream>>>(eo_ws, entry_slot_ws, cw_out, out);
}

// Round 9
// 542.364 us; speedup vs baseline: 1.1392x; 1.0439x over previous
//
// Ernie4.5 MoE MLP — MI355X gfx950
// R9: delete the 3 wcvt pre-passes (~190us of pure streaming). Both GEMMs
//     reg-stage B from ORIGINAL fp32 weights: coalesced row loads -> in-reg
//     f2bf -> ds_write_b128 into the R2/R4/R5-verified subtiled layout ->
//     tr_b16 fragment reads (verified contract). 3-buffer distance-2 pipeline,
//     one barrier/iter, counted vmcnt(5), T14 write-late, dual reg sets
//     (macro unroll-by-2, all static register names).
// ws peak ~121 MB. eo aliases adisp (dead after gemm1).
#include <hip/hip_runtime.h>
#include <hip/hip_bf16.h>

constexpr int S_TOK = 16384;
constexpr int HDIM  = 1024;
constexpr int IDIM  = 512;
constexpr int NEXP  = 64;
constexpr int CAPC  = 640;
constexpr int NCHUNK = 128;   // 32768 routing entries / 256

typedef __attribute__((ext_vector_type(8))) short bf16x8;
typedef __attribute__((ext_vector_type(4))) short short4v;
typedef __attribute__((ext_vector_type(4))) float f32x4;

__device__ __forceinline__ float bf2f(unsigned short u){
  return __uint_as_float(((unsigned)u) << 16);
}
__device__ __forceinline__ unsigned short f2bf(float f){   // RNE bf16 (inputs finite)
  unsigned u = __float_as_uint(f);
  return (unsigned short)((u + 0x7fffu + ((u >> 16) & 1u)) >> 16);
}
__device__ __forceinline__ unsigned pk2(float a, float b){
  return (unsigned)f2bf(a) | ((unsigned)f2bf(b) << 16);
}
__device__ __forceinline__ void gload_lds16(const void* g, void* l){
  __builtin_amdgcn_global_load_lds((const __attribute__((address_space(1))) unsigned*)g,
                                   (__attribute__((address_space(3))) unsigned*)l, 16, 0, 0);
}
__device__ __forceinline__ unsigned ldsoff(const void* p){ return (unsigned)(size_t)p; }
// two hw-transpose reads: parity-0 block and parity-1 block (+512B)
__device__ __forceinline__ void trread2(unsigned addr, short4v& lo, short4v& hi){
  asm volatile("ds_read_b64_tr_b16 %0, %2\n\t"
               "ds_read_b64_tr_b16 %1, %2 offset:512"
               : "=&v"(lo), "=&v"(hi) : "v"(addr));
}

// ---------------- gate: logits (fp32 exact), softmax, top-2 -------------------
__global__ __launch_bounds__(256) void gate_kernel(
    const float* __restrict__ x, const float* __restrict__ wgate,
    float* __restrict__ logits_out, float* __restrict__ topk_p,
    int* __restrict__ flat_e, float* __restrict__ rl_out)
{
  __shared__ float xs[4][HDIM];
  const int w = threadIdx.x >> 6, lane = threadIdx.x & 63;
  const int tok = blockIdx.x * 4 + w;
  const float4* xr = (const float4*)(x + (size_t)tok * HDIM);
  float4* xd = (float4*)(&xs[w][0]);
#pragma unroll
  for (int j = 0; j < 4; ++j) xd[j * 64 + lane] = xr[j * 64 + lane];
  __syncthreads();
  float acc = 0.f;
#pragma unroll 8
  for (int h = 0; h < HDIM; ++h)
    acc = fmaf(xs[w][h], wgate[h * NEXP + lane], acc);
  logits_out[(size_t)tok * NEXP + lane] = acc;
  float m = acc;
#pragma unroll
  for (int d = 1; d < 64; d <<= 1) m = fmaxf(m, __shfl_xor(m, d));
  float p = expf(acc - m);
  float sum = p;
#pragma unroll
  for (int d = 1; d < 64; d <<= 1) sum += __shfl_xor(sum, d);
  float prob = p / sum;
  float v = prob; int idx = lane;
#pragma unroll
  for (int d = 1; d < 64; d <<= 1){
    float ov = __shfl_xor(v, d); int oi = __shfl_xor(idx, d);
    if (ov > v || (ov == v && oi < idx)){ v = ov; idx = oi; }
  }
  const int e1 = idx; const float p1 = v;
  v = (lane == e1) ? -1.f : prob; idx = lane;
#pragma unroll
  for (int d = 1; d < 64; d <<= 1){
    float ov = __shfl_xor(v, d); int oi = __shfl_xor(idx, d);
    if (ov > v || (ov == v && oi < idx)){ v = ov; idx = oi; }
  }
  if (lane == 0){
    flat_e[tok * 2]     = e1;  flat_e[tok * 2 + 1] = idx;
    topk_p[tok * 2]     = p1;  topk_p[tok * 2 + 1] = v;
  }
  if (tok == 0 && lane == 0) rl_out[0] = 0.f;
}

// ---------------- per-chunk expert histogram ---------------------------------
__global__ __launch_bounds__(256) void hist_kernel(const int* __restrict__ flat_e,
                                                   int* __restrict__ counts)
{
  __shared__ int hh[NEXP];
  const int t = threadIdx.x;
  if (t < NEXP) hh[t] = 0;
  __syncthreads();
  const int e = flat_e[blockIdx.x * 256 + t];
  atomicAdd(&hh[e], 1);
  __syncthreads();
  if (t < NEXP) counts[blockIdx.x * NEXP + t] = hh[t];
}

// ---------------- per-expert exclusive scan over chunks ----------------------
__global__ __launch_bounds__(256) void offsets_kernel(const int* __restrict__ counts,
                                                      int* __restrict__ offs,
                                                      int* __restrict__ etot)
{
  const int w = threadIdx.x >> 6, lane = threadIdx.x & 63;
  const int e = blockIdx.x * 4 + w;
  int v0 = counts[lane * NEXP + e];
  int v1 = counts[(64 + lane) * NEXP + e];
  int s0 = v0, s1 = v1;
#pragma unroll
  for (int d = 1; d < 64; d <<= 1){
    int n0 = __shfl_up(s0, d); if (lane >= d) s0 += n0;
    int n1 = __shfl_up(s1, d); if (lane >= d) s1 += n1;
  }
  const int tot0 = __shfl(s0, 63);
  offs[lane * NEXP + e]        = s0 - v0;
  offs[(64 + lane) * NEXP + e] = tot0 + s1 - v1;
  if (lane == 63) etot[e] = tot0 + s1;
}

// ---------------- ordered placement + slot map + cw --------------------------
__global__ __launch_bounds__(256) void place_kernel(
    const int* __restrict__ flat_e, const float* __restrict__ topk_p,
    const int* __restrict__ offs, int* __restrict__ entry_slot,
    int* __restrict__ token_of_slot, float* __restrict__ cw_out)
{
  __shared__ int es[256];
  __shared__ float wsh[256];
  const int t = threadIdx.x;
  const int i = blockIdx.x * 256 + t;
  const int e = flat_e[i];
  es[t] = e;
  __syncthreads();
  int local = 0;
  for (int j = 0; j < t; ++j) local += (es[j] == e);
  const int pos = offs[blockIdx.x * NEXP + e] + local;
  const bool valid = pos < CAPC;
  const int slot = e * CAPC + pos;
  entry_slot[i] = valid ? slot : -1;
  if (valid) token_of_slot[slot] = i >> 1;
  const float p = topk_p[i];
  wsh[t] = valid ? p : 0.f;
  __syncthreads();
  const float wme = wsh[t], wo = wsh[t ^ 1];
  cw_out[i] = wme / fmaxf(wme + wo, 1e-12f);
}

// ---------------- build dispatched A (bf16) ----------------------------------
__global__ __launch_bounds__(256) void adisp_kernel(
    const float* __restrict__ x, const int* __restrict__ token_of_slot,
    const int* __restrict__ etot, unsigned short* __restrict__ adisp)
{
  const int slot = blockIdx.x;
  const int e = slot / CAPC, c = slot - e * CAPC;
  int cnt = etot[e]; if (cnt > CAPC) cnt = CAPC;
  if (c >= cnt) return;
  const int tok = token_of_slot[slot];
  const int t = threadIdx.x;
  float4 v = ((const float4*)(x + (size_t)tok * HDIM))[t];
  ushort4 o; o.x = f2bf(v.x); o.y = f2bf(v.y); o.z = f2bf(v.z); o.w = f2bf(v.w);
  ((ushort4*)(adisp + (size_t)slot * HDIM))[t] = o;
}

// A tile [128 rows][32 k] bf16: gload_lds w16, linear dest, source octet
// pre-swizzled: unit c -> row=c>>2, jsrc=(c&3)^((row>>1)&3); fragment read
// ds_read_b128 at row*32 + ((lane>>4)^((row>>1)&3))*8. (Verified R4/R5/R7/R8.)
// B panel [32 k][128 n] bf16, subtiled for tr_b16 (verified R2/R4/R5):
//   k = 8g+4par+dk, n = 16ng+8h8; ushort off = ((ng*2+par)*4+g)*64+dk*16+h8*8.
//   Staged by reg: thread (k=t>>4, n0=(t&15)*8) loads 8 fp32 along n, converts,
//   one uint4 ds_write per panel. tr-read pair: addr = cg*1024+8*lane, +512.

// ---------------- gemm1: fused g,u + SwiGLU; fp32 B in-GEMM ------------------
__global__ __launch_bounds__(512, 2) void gemm1_kernel(
    const unsigned short* __restrict__ adisp,
    const float* __restrict__ wg, const float* __restrict__ wu,
    unsigned short* __restrict__ hbuf)
{
  constexpr int NK1 = HDIM / 32;               // 32 K-steps
  __shared__ unsigned short As[3][128 * 32];   // 8 KB each
  __shared__ unsigned short Bs[3][2 * 128 * 32]; // panelG + panelU, 16 KB each
  const int bb = blockIdx.x;
  const int lb = (bb & 7) * 160 + (bb >> 3);   // 1280 blocks, 1280%8==0
  const int e = lb / 20; const int r2 = lb - e * 20;
  const int nt = r2 / 5, mt = r2 - nt * 5;     // mt innermost: 5 share B panel
  const int t = threadIdx.x, w = t >> 6, lane = t & 63;
  const int wr = w >> 2, wc = w & 3;           // 2m x 4n waves
  const size_t arow0 = (size_t)e * CAPC + (size_t)mt * 128;
  const unsigned short* abase = adisp + arow0 * HDIM;
  const float* gsrc = wg + (size_t)e * HDIM * IDIM + nt * 128;
  const float* usrc = wu + (size_t)e * HDIM * IDIM + nt * 128;

  int aoff; { int row = t >> 2, jsrc = (t & 3) ^ ((row >> 1) & 3);
              aoff = row * HDIM + jsrc * 8; }
  const int bk = t >> 4, bn0 = (t & 15) * 8;   // thread's (k, n0) in panel
  const int bgo = bk * IDIM + bn0;             // fp32 source offset (+kb*IDIM)
  const int g_ = bk >> 3, par = (bk >> 2) & 1, dk = bk & 3;
  const int ng = bn0 >> 4, h8 = (bn0 >> 3) & 1;
  const unsigned bwo = (unsigned)((((ng * 2 + par) * 4 + g_) * 64) + dk * 16 + h8 * 8);

  f32x4 ag[4][2], au[4][2];
#pragma unroll
  for (int i = 0; i < 4; ++i)
#pragma unroll
    for (int j = 0; j < 2; ++j)
#pragma unroll
      for (int q = 0; q < 4; ++q){ ag[i][j][q] = 0.f; au[i][j][q] = 0.f; }

  float4 g0a, g0b, u0a, u0b, g1a, g1b, u1a, u1b;

#define G1_LOAD(KB, RA, RB, RC, RD) {                                          \
    const float* gp_ = gsrc + (size_t)(KB) * IDIM + bgo;                       \
    const float* up_ = usrc + (size_t)(KB) * IDIM + bgo;                       \
    RA = *(const float4*)gp_;       RB = *(const float4*)(gp_ + 4);            \
    RC = *(const float4*)up_;       RD = *(const float4*)(up_ + 4); }

#define G1_STORE(NB, WA, WB, WC, WD) {                                         \
    *(uint4*)&Bs[NB][bwo] = make_uint4(pk2(WA.x,WA.y), pk2(WA.z,WA.w),         \
                                       pk2(WB.x,WB.y), pk2(WB.z,WB.w));        \
    *(uint4*)&Bs[NB][4096 + bwo] = make_uint4(pk2(WC.x,WC.y), pk2(WC.z,WC.w),  \
                                       pk2(WD.x,WD.y), pk2(WD.z,WD.w)); }

#define G1_STEP(TI, LA, LB, LC, LD, WA, WB, WC, WD) {                          \
    const int cur_ = (TI) % 3;                                                 \
    const bool pf_ = (TI) + 2 < NK1;                                           \
    if (pf_){                                                                  \
      const int kb2_ = ((TI) + 2) * 32;                                        \
      gload_lds16(abase + aoff + kb2_, &As[((TI) + 2) % 3][w * 64 * 8]);       \
      G1_LOAD(kb2_, LA, LB, LC, LD);                                           \
    }                                                                          \
    { const int j8_ = lane >> 4;                                               \
      bf16x8 af_[4], bg_[2], bu_[2];                                           \
      _Pragma("unroll")                                                        \
      for (int m = 0; m < 4; ++m){                                             \
        int row_ = wr * 64 + m * 16 + (lane & 15);                             \
        af_[m] = *(const bf16x8*)&As[cur_][row_ * 32 + ((j8_ ^ ((row_ >> 1) & 3)) * 8)]; \
      }                                                                        \
      const unsigned b0_ = ldsoff(&Bs[cur_][0]);                               \
      _Pragma("unroll")                                                        \
      for (int n = 0; n < 2; ++n){                                             \
        unsigned ao_ = (unsigned)((wc * 2 + n) * 1024 + lane * 8);             \
        short4v l0_, l1_, m0_, m1_;                                            \
        trread2(b0_ + ao_, l0_, l1_);                                          \
        bg_[n] = __builtin_shufflevector(l0_, l1_, 0,1,2,3,4,5,6,7);           \
        trread2(b0_ + 8192 + ao_, m0_, m1_);                                   \
        bu_[n] = __builtin_shufflevector(m0_, m1_, 0,1,2,3,4,5,6,7);           \
      }                                                                        \
      asm volatile("s_waitcnt lgkmcnt(0)" ::: "memory");                       \
      __builtin_amdgcn_sched_barrier(0);                                       \
      __builtin_amdgcn_s_setprio(1);                                           \
      _Pragma("unroll")                                                        \
      for (int m = 0; m < 4; ++m)                                              \
        _Pragma("unroll")                                                      \
        for (int n = 0; n < 2; ++n){                                           \
          ag[m][n] = __builtin_amdgcn_mfma_f32_16x16x32_bf16(af_[m], bg_[n], ag[m][n], 0, 0, 0); \
          au[m][n] = __builtin_amdgcn_mfma_f32_16x16x32_bf16(af_[m], bu_[n], au[m][n], 0, 0, 0); \
        }                                                                      \
      __builtin_amdgcn_s_setprio(0);                                           \
    }                                                                          \
    if ((TI) + 1 < NK1){                                                       \
      if (pf_) asm volatile("s_waitcnt vmcnt(5)" ::: "memory");                \
      else     asm volatile("s_waitcnt vmcnt(0)" ::: "memory");                \
      G1_STORE(((TI) + 1) % 3, WA, WB, WC, WD);                                \
    }                                                                          \
    asm volatile("s_waitcnt lgkmcnt(0)" ::: "memory");                         \
    __builtin_amdgcn_s_barrier();                                              \
    __builtin_amdgcn_sched_barrier(0);                                         \
  }

  // prologue: tiles 0,1 in flight (A via gload_lds, B via regs)
  gload_lds16(abase + aoff + 0,  &As[0][w * 64 * 8]);
  G1_LOAD(0,  g0a, g0b, u0a, u0b);
  gload_lds16(abase + aoff + 32, &As[1][w * 64 * 8]);
  G1_LOAD(32, g1a, g1b, u1a, u1b);
  asm volatile("s_waitcnt vmcnt(5)" ::: "memory");   // tile 0 landed
  G1_STORE(0, g0a, g0b, u0a, u0b);
  asm volatile("s_waitcnt lgkmcnt(0)" ::: "memory");
  __builtin_amdgcn_s_barrier();

  for (int tb = 0; tb < NK1; tb += 2){
    G1_STEP(tb,     g0a, g0b, u0a, u0b,  g1a, g1b, u1a, u1b);
    G1_STEP(tb + 1, g1a, g1b, u1a, u1b,  g0a, g0b, u0a, u0b);
  }
#undef G1_STEP
#undef G1_STORE
#undef G1_LOAD

  // epilogue: h = silu(g)*u -> bf16
#pragma unroll
  for (int m = 0; m < 4; ++m)
#pragma unroll
    for (int n = 0; n < 2; ++n)
#pragma unroll
      for (int q = 0; q < 4; ++q){
        int row = wr * 64 + m * 16 + (lane >> 4) * 4 + q;
        int col = nt * 128 + wc * 32 + n * 16 + (lane & 15);
        float gv = ag[m][n][q], uv = au[m][n][q];
        float hv = gv / (1.f + expf(-gv)) * uv;
        hbuf[(arow0 + row) * IDIM + col] = f2bf(hv);
      }
}

// ---------------- gemm2: eo = h * Wd; fp32 B in-GEMM -------------------------
__global__ __launch_bounds__(512, 2) void gemm2_kernel(
    const unsigned short* __restrict__ hbuf,
    const float* __restrict__ wd,
    unsigned short* __restrict__ eo)
{
  constexpr int NK2 = IDIM / 32;               // 16 K-steps
  __shared__ unsigned short As[3][128 * 32];
  __shared__ unsigned short Bs[3][2 * 128 * 32];  // two 128-n panels
  const int bb = blockIdx.x;
  const int lb = (bb & 7) * 160 + (bb >> 3);   // 1280 blocks
  const int e = lb / 20; const int r2 = lb - e * 20;
  const int nt = r2 / 5, mt = r2 - nt * 5;
  const int t = threadIdx.x, w = t >> 6, lane = t & 63;
  const int wr = w >> 2, wc = w & 3;
  const size_t arow0 = (size_t)e * CAPC + (size_t)mt * 128;
  const unsigned short* abase = hbuf + arow0 * IDIM;
  const float* dsrc = wd + (size_t)e * IDIM * HDIM + nt * 256;

  int aoff; { int row = t >> 2, jsrc = (t & 3) ^ ((row >> 1) & 3);
              aoff = row * IDIM + jsrc * 8; }
  const int bk = t >> 4, bn0 = (t & 15) * 8;
  const int bgo = bk * HDIM + bn0;
  const int g_ = bk >> 3, par = (bk >> 2) & 1, dk = bk & 3;
  const int ng = bn0 >> 4, h8 = (bn0 >> 3) & 1;
  const unsigned bwo = (unsigned)((((ng * 2 + par) * 4 + g_) * 64) + dk * 16 + h8 * 8);

  f32x4 ac[4][4];
#pragma unroll
  for (int i = 0; i < 4; ++i)
#pragma unroll
    for (int j = 0; j < 4; ++j)
#pragma unroll
      for (int q = 0; q < 4; ++q) ac[i][j][q] = 0.f;

  float4 p0a, p0b, p1a, p1b, q0a, q0b, q1a, q1b;

#define G2_LOAD(KB, RA, RB, RC, RD) {                                          \
    const float* gp_ = dsrc + (size_t)(KB) * HDIM + bgo;                       \
    RA = *(const float4*)gp_;         RB = *(const float4*)(gp_ + 4);          \
    RC = *(const float4*)(gp_ + 128); RD = *(const float4*)(gp_ + 132); }

#define G2_STORE(NB, WA, WB, WC, WD) {                                         \
    *(uint4*)&Bs[NB][bwo] = make_uint4(pk2(WA.x,WA.y), pk2(WA.z,WA.w),         \
                                       pk2(WB.x,WB.y), pk2(WB.z,WB.w));        \
    *(uint4*)&Bs[NB][4096 + bwo] = make_uint4(pk2(WC.x,WC.y), pk2(WC.z,WC.w),  \
                                       pk2(WD.x,WD.y), pk2(WD.z,WD.w)); }

#define G2_STEP(TI, LA, LB, LC, LD, WA, WB, WC, WD) {                          \
    const int cur_ = (TI) % 3;                                                 \
    const bool pf_ = (TI) + 2 < NK2;                                           \
    if (pf_){                                                                  \
      const int kb2_ = ((TI) + 2) * 32;                                        \
      gload_lds16(abase + aoff + kb2_, &As[((TI) + 2) % 3][w * 64 * 8]);       \
      G2_LOAD(kb2_, LA, LB, LC, LD);                                           \
    }                                                                          \
    { const int j8_ = lane >> 4;                                               \
      bf16x8 af_[4], bf_[4];                                                   \
      _Pragma("unroll")                                                        \
      for (int m = 0; m < 4; ++m){                                             \
        int row_ = wr * 64 + m * 16 + (lane & 15);                             \
        af_[m] = *(const bf16x8*)&As[cur_][row_ * 32 + ((j8_ ^ ((row_ >> 1) & 3)) * 8)]; \
      }                                                                        \
      const unsigned b0_ = ldsoff(&Bs[cur_][0]) + (unsigned)(wc >> 1) * 8192;  \
      _Pragma("unroll")                                                        \
      for (int n = 0; n < 4; ++n){                                             \
        unsigned ao_ = (unsigned)(((wc & 1) * 4 + n) * 1024 + lane * 8);       \
        short4v l0_, l1_;                                                      \
        trread2(b0_ + ao_, l0_, l1_);                                          \
        bf_[n] = __builtin_shufflevector(l0_, l1_, 0,1,2,3,4,5,6,7);           \
      }                                                                        \
      asm volatile("s_waitcnt lgkmcnt(0)" ::: "memory");                       \
      __builtin_amdgcn_sched_barrier(0);                                       \
      __builtin_amdgcn_s_setprio(1);                                           \
      _Pragma("unroll")                                                        \
      for (int m = 0; m < 4; ++m)                                              \
        _Pragma("unroll")                                                      \
        for (int n = 0; n < 4; ++n)                                            \
          ac[m][n] = __builtin_amdgcn_mfma_f32_16x16x32_bf16(af_[m], bf_[n], ac[m][n], 0, 0, 0); \
      __builtin_amdgcn_s_setprio(0);                                           \
    }                                                                          \
    if ((TI) + 1 < NK2){                                                       \
      if (pf_) asm volatile("s_waitcnt vmcnt(5)" ::: "memory");                \
      else     asm volatile("s_waitcnt vmcnt(0)" ::: "memory");                \
      G2_STORE(((TI) + 1) % 3, WA, WB, WC, WD);                                \
    }                                                                          \
    asm volatile("s_waitcnt lgkmcnt(0)" ::: "memory");                         \
    __builtin_amdgcn_s_barrier();                                              \
    __builtin_amdgcn_sched_barrier(0);                                         \
  }

  gload_lds16(abase + aoff + 0,  &As[0][w * 64 * 8]);
  G2_LOAD(0,  p0a, p0b, q0a, q0b);
  gload_lds16(abase + aoff + 32, &As[1][w * 64 * 8]);
  G2_LOAD(32, p1a, p1b, q1a, q1b);
  asm volatile("s_waitcnt vmcnt(5)" ::: "memory");
  G2_STORE(0, p0a, p0b, q0a, q0b);
  asm volatile("s_waitcnt lgkmcnt(0)" ::: "memory");
  __builtin_amdgcn_s_barrier();

  for (int tb = 0; tb < NK2; tb += 2){
    G2_STEP(tb,     p0a, p0b, q0a, q0b,  p1a, p1b, q1a, q1b);
    G2_STEP(tb + 1, p1a, p1b, q1a, q1b,  p0a, p0b, q0a, q0b);
  }
#undef G2_STEP
#undef G2_STORE
#undef G2_LOAD

#pragma unroll
  for (int m = 0; m < 4; ++m)
#pragma unroll
    for (int n = 0; n < 4; ++n)
#pragma unroll
      for (int q = 0; q < 4; ++q){
        int row = wr * 64 + m * 16 + (lane >> 4) * 4 + q;
        int col = nt * 256 + wc * 64 + n * 16 + (lane & 15);
        eo[(arow0 + row) * HDIM + col] = f2bf(ac[m][n][q]);
      }
}

// ---------------- combine: out[s] = sum_k cw[s,k] * eo[slot(s,k)] ------------
__global__ __launch_bounds__(256) void combine_kernel(
    const unsigned short* __restrict__ eo, const int* __restrict__ entry_slot,
    const float* __restrict__ cw, float* __restrict__ out)
{
  const int s = blockIdx.x, t = threadIdx.x;
  const int s0 = entry_slot[2 * s], s1 = entry_slot[2 * s + 1];
  const float w0 = cw[2 * s], w1 = cw[2 * s + 1];
  const int c = t * 4;
  float r0 = 0.f, r1 = 0.f, r2 = 0.f, r3 = 0.f;
  if (s0 >= 0){
    ushort4 vq = *(const ushort4*)&eo[(size_t)s0 * HDIM + c];
    r0 += w0 * bf2f(vq.x); r1 += w0 * bf2f(vq.y); r2 += w0 * bf2f(vq.z); r3 += w0 * bf2f(vq.w);
  }
  if (s1 >= 0){
    ushort4 vq = *(const ushort4*)&eo[(size_t)s1 * HDIM + c];
    r0 += w1 * bf2f(vq.x); r1 += w1 * bf2f(vq.y); r2 += w1 * bf2f(vq.z); r3 += w1 * bf2f(vq.w);
  }
  ((float4*)(out + (size_t)s * HDIM))[t] = make_float4(r0, r1, r2, r3);
}

extern "C" void kernel_launch(void* const* d_in, const int* in_sizes, int n_in,
                              void* d_out, int out_size, void* d_ws, size_t ws_size,
                              hipStream_t stream) {
  (void)in_sizes; (void)n_in; (void)out_size; (void)ws_size;
  const float* x     = (const float*)d_in[0];
  const float* wgate = (const float*)d_in[1];
  const float* wg    = (const float*)d_in[2];
  const float* wu    = (const float*)d_in[3];
  const float* wd    = (const float*)d_in[4];

  float* out        = (float*)d_out;                         // [S,H]
  float* cw_out     = out + (size_t)S_TOK * HDIM;            // [S,2]
  float* rl_out     = cw_out + (size_t)S_TOK * 2;            // [1]
  float* logits_out = rl_out + 1;                            // [S,64]

  char* w8 = (char*)d_ws;
  size_t off = 0;
  auto alloc = [&](size_t bytes){ size_t r = off; off += (bytes + 255) & ~(size_t)255; return r; };
  int*   flat_e_ws        = (int*)  (w8 + alloc((size_t)32768 * 4));
  float* topk_p_ws        = (float*)(w8 + alloc((size_t)32768 * 4));
  int*   counts_ws        = (int*)  (w8 + alloc((size_t)NCHUNK * NEXP * 4));
  int*   offs_ws          = (int*)  (w8 + alloc((size_t)NCHUNK * NEXP * 4));
  int*   etot_ws          = (int*)  (w8 + alloc((size_t)NEXP * 4));
  int*   entry_slot_ws    = (int*)  (w8 + alloc((size_t)32768 * 4));
  int*   token_of_slot_ws = (int*)  (w8 + alloc((size_t)NEXP * CAPC * 4));
  unsigned short* hbuf_ws = (unsigned short*)(w8 + alloc((size_t)NEXP * CAPC * IDIM * 2));
  unsigned short* adisp_ws= (unsigned short*)(w8 + alloc((size_t)NEXP * CAPC * HDIM * 2));
  unsigned short* eo_ws   = adisp_ws;   // alias: adisp dead after gemm1

  gate_kernel   <<<S_TOK / 4, 256, 0, stream>>>(x, wgate, logits_out, topk_p_ws, flat_e_ws, rl_out);
  hist_kernel   <<<NCHUNK,    256, 0, stream>>>(flat_e_ws, counts_ws);
  offsets_kernel<<<16,        256, 0, stream>>>(counts_ws, offs_ws, etot_ws);
  place_kernel  <<<NCHUNK,    256, 0, stream>>>(flat_e_ws, topk_p_ws, offs_ws,
                                                entry_slot_ws, token_of_slot_ws, cw_out);
  adisp_kernel  <<<NEXP * CAPC, 256, 0, stream>>>(x, token_of_slot_ws, etot_ws, adisp_ws);
  gemm1_kernel  <<<NEXP * 20, 512, 0, stream>>>(adisp_ws, wg, wu, hbuf_ws);
  gemm2_kernel  <<<NEXP * 20, 512, 0, stream>>>(hbuf_ws, wd, eo_ws);
  combine_kernel<<<S_TOK,     256, 0, stream>>>(eo_ws, entry_slot_ws, cw_out, out);
}